// Round 16
// baseline (164.504 us; speedup 1.0000x reference)
//
#include <hip/hip_runtime.h>
#include <hip/hip_bf16.h>
#include <stdint.h>

typedef unsigned short u16;
typedef __bf16 bf16x8 __attribute__((ext_vector_type(8)));
typedef float  f32x4  __attribute__((ext_vector_type(4)));
typedef u16    u16x8  __attribute__((ext_vector_type(8)));
typedef u16    u16x4  __attribute__((ext_vector_type(4)));

// float -> bf16 RNE
__device__ __forceinline__ u16 f2bf(float f) {
  union { float f; unsigned u; } v; v.f = f;
  unsigned u = v.u;
  unsigned r = u + 0x7FFFu + ((u >> 16) & 1u);
  return (u16)(r >> 16);
}

__device__ __forceinline__ void gld_lds16(const void* g, void* l) {
  __builtin_amdgcn_global_load_lds(
      (const __attribute__((address_space(1))) void*)g,
      (__attribute__((address_space(3))) void*)l, 16, 0, 0);
}

// ---- detect int32 vs int64 index storage ----------------------------------
__global__ void detect_idx_width(const unsigned* __restrict__ w, int* __restrict__ flag) {
  unsigned v = w[threadIdx.x * 2 + 1];
  unsigned long long any = __ballot(v != 0u);
  if (threadIdx.x == 0) *flag = (any != 0ull) ? 1 : 0;  // 1 = int32, 0 = int64
}

// ---- fused prepass: x f32->bf16 AND W dequant ------------------------------
__global__ __launch_bounds__(256) void prepass_kernel(
    const float4* __restrict__ x, u16* __restrict__ xb, long n8,
    const int4* __restrict__ widx, const float* __restrict__ values,
    u16* __restrict__ wb, const int* __restrict__ flag, long n4) {
  const long gid = (long)blockIdx.x * blockDim.x + threadIdx.x;
  const long stride = (long)gridDim.x * blockDim.x;
  for (long i = gid; i < n8; i += stride) {
    float4 a = x[2 * i];
    float4 b = x[2 * i + 1];
    u16x8 r;
    r[0] = f2bf(a.x); r[1] = f2bf(a.y); r[2] = f2bf(a.z); r[3] = f2bf(a.w);
    r[4] = f2bf(b.x); r[5] = f2bf(b.y); r[6] = f2bf(b.z); r[7] = f2bf(b.w);
    *(u16x8*)(xb + 8 * i) = r;
  }
  const bool is32 = (*flag != 0);
  for (long i = gid; i < n4; i += stride) {
    int i0, i1, i2, i3;
    if (is32) {
      int4 v = widx[i];
      i0 = v.x; i1 = v.y; i2 = v.z; i3 = v.w;
    } else {
      int4 a = widx[2 * i];
      int4 b = widx[2 * i + 1];
      i0 = a.x; i1 = a.z; i2 = b.x; i3 = b.z;
    }
    u16x4 r;
    r[0] = f2bf(values[i0]); r[1] = f2bf(values[i1]);
    r[2] = f2bf(values[i2]); r[3] = f2bf(values[i3]);
    *(u16x4*)(wb + 4 * i) = r;
  }
}

// ===========================================================================
// 256x256 bf16 GEMM — R16 = R12's verified interleaved kernel (106.2us,
// MfmaUtil 60%) + T5: each phase body wrapped in s_setprio(1)/(0). Waves
// in the compute body run at prio 1; waves spinning at the phase barrier
// drop to prio 0 -> CU arbitration favors MFMA-issuing waves (m218b/m224:
// +21-39% on phase-split structures). SGB weave untouched.
// ===========================================================================
#define VMW(n) asm volatile("s_waitcnt vmcnt(" #n ")" ::: "memory")
#define PH_BAR asm volatile("s_barrier" ::: "memory")
#define SGB(m, n) __builtin_amdgcn_sched_group_barrier((m), (n), 0)
#define NOWT (void)0

__global__ __launch_bounds__(512, 1) void gemm256_kernel(
    const u16* __restrict__ Xb, const u16* __restrict__ Wb,
    const float* __restrict__ bias, float* __restrict__ C,
    int Nout, int Kin) {
  __shared__ __align__(16) char lds[163840];  // A:[0,64K) 2 bufs; B:[64K,160K) 3 bufs

  const int tid  = threadIdx.x;
  const int lane = tid & 63;
  const int wave = tid >> 6;
  const int wr = wave >> 2;   // 0..1  (M half)
  const int wc = wave & 3;    // 0..3  (N quarter)

  // bijective XCD swizzle (m204)
  const int nwg = gridDim.x;
  const int bid = blockIdx.x;
  const int q8 = nwg >> 3, r8 = nwg & 7;
  const int xcd = bid & 7;
  const int wg = (xcd < r8 ? xcd * (q8 + 1) : r8 * (q8 + 1) + (xcd - r8) * q8) + (bid >> 3);

  const int tiles_n = Nout / 256;
  const long brow = (long)(wg / tiles_n) * 256;
  const long bcol = (long)(wg % tiles_n) * 256;

  const long rowb  = (long)Kin * 2;     // row bytes
  const long rstep = 64 * rowb;         // +64 rows (uniform)
  const long hstep = 128 * rowb;        // +128 rows (uniform)

  // staging: inverse-swizzled global source + linear LDS dest (rule #21)
  const int f0  = tid * 16;
  const int f1  = f0 + 8192;
  const int rS0 = f0 >> 7;
  const int cS  = (f0 & 127) ^ ((rS0 & 7) << 4);
  const int voff = (int)(rS0 * rowb) + cS;

  const char* uA = (const char*)Xb + (size_t)brow * rowb;
  const char* uB = (const char*)Wb + (size_t)bcol * rowb;

// single gld_lds (h = row-half source, part = rows 0-63 / 64-127)
#define SA1(base_, h, t, part) \
  gld_lds16(uA + (size_t)(h) * hstep + (size_t)(t) * 128 + ((part) ? rstep : 0) + voff, \
            lds + (base_) + (h) * 16384 + ((part) ? f1 : f0))
#define SB1(base_, h, t, part) \
  gld_lds16(uB + (size_t)(h) * hstep + (size_t)(t) * 128 + ((part) ? rstep : 0) + voff, \
            lds + (base_) + (h) * 16384 + ((part) ? f1 : f0))

  // fragment read addressing (swizzled), hoisted to address ints
  const int fr   = lane & 15;
  const int kb   = (lane >> 4) * 16;
  const int xsw  = (fr & 7) << 4;
  const int colx0 = kb ^ xsw;
  const int colx1 = (64 + kb) ^ xsw;
  const int aOff = wr * 16384 + fr * 128;
  const int bOff = (wc >> 1) * 16384 + ((wc & 1) * 64 + fr) * 128;
  const int aAdr0 = aOff + colx0;
  const int aAdr1 = aOff + colx1;
  int b0k0 = 65536  + bOff + colx0, b0k1 = 65536  + bOff + colx1;
  int b1k0 = 98304  + bOff + colx0, b1k1 = 98304  + bOff + colx1;
  int b2k0 = 131072 + bOff + colx0, b2k1 = 131072 + bOff + colx1;

  bf16x8 afrA[2][2];   // MFMA(q) consumes afrA if q even, afrB if q odd
  bf16x8 afrB[2][2];
  bf16x8 bfrE[4][2];   // B-frags, even tiles
  bf16x8 bfrO[4][2];   // B-frags, odd tiles
  f32x4  acc[8][4] = {};

#define RDA(aBase_, q, DST, m2, ks) \
  DST[(m2)][(ks)] = *(const bf16x8*)(lds + ((ks) ? aAdr1 : aAdr0) + (aBase_) + (q) * 4096 + (m2) * 2048)
#define RDB(bk, DST, ni, ks) \
  DST[(ni)][(ks)] = *(const bf16x8*)(lds + (bk) + (ni) * 2048)

#define MFMA1(d, a, b) d = __builtin_amdgcn_mfma_f32_16x16x32_bf16((a), (b), (d), 0, 0, 0)
#define MM2(q, m2, ni, AF, BF) { \
  MFMA1(acc[(q)*2+(m2)][(ni)], AF[(m2)][0], BF[(ni)][0]); \
  MFMA1(acc[(q)*2+(m2)][(ni)], AF[(m2)][1], BF[(ni)][1]); }

// Phase: 16 MFMA interleaved 2:1 with 6 ds_reads + 2 gld_lds (T19 pattern),
// body wrapped in setprio(1)/(0) (T5).
#define PHASE(q, AF, BF, R0, R1, R2, R3, R4, R5, S0, S1, WT) { \
  __builtin_amdgcn_s_setprio(1); \
  MM2(q, 0, 0, AF, BF); SGB(0x8, 2); R0; SGB(0x100, 1); \
  MM2(q, 1, 0, AF, BF); SGB(0x8, 2); R1; SGB(0x100, 1); \
  MM2(q, 0, 1, AF, BF); SGB(0x8, 2); R2; SGB(0x100, 1); \
  MM2(q, 1, 1, AF, BF); SGB(0x8, 2); R3; SGB(0x100, 1); \
  MM2(q, 0, 2, AF, BF); SGB(0x8, 2); R4; SGB(0x100, 1); \
  MM2(q, 1, 2, AF, BF); SGB(0x8, 2); R5; SGB(0x100, 1); \
  MM2(q, 0, 3, AF, BF); SGB(0x8, 2); S0; SGB(0x70, 1); \
  MM2(q, 1, 3, AF, BF); SGB(0x8, 2); S1; SGB(0x70, 1); \
  __builtin_amdgcn_s_setprio(0); \
  WT; PH_BAR; }

  const int aB0 = 0, aB1 = 32768;
  int bR0 = 65536, bR1 = 98304, bR2 = 131072;  // LDS byte bases for staging
  const int NT = Kin >> 6;

  // prologue: A(0)->aB0, B(0..2); drain; preload bfrE=B(0), afrA=A(0,q0)
  SA1(aB0, 0, 0, 0); SA1(aB0, 0, 0, 1); SA1(aB0, 1, 0, 0); SA1(aB0, 1, 0, 1);
  SB1(bR0, 0, 0, 0); SB1(bR0, 0, 0, 1); SB1(bR0, 1, 0, 0); SB1(bR0, 1, 0, 1);
  SB1(bR1, 0, 1, 0); SB1(bR1, 0, 1, 1); SB1(bR1, 1, 1, 0); SB1(bR1, 1, 1, 1);
  SB1(bR2, 0, 2, 0); SB1(bR2, 0, 2, 1); SB1(bR2, 1, 2, 0); SB1(bR2, 1, 2, 1);
  VMW(0);
  PH_BAR;
  RDB(b0k0, bfrE, 0, 0); RDB(b0k1, bfrE, 0, 1); RDB(b0k0, bfrE, 1, 0); RDB(b0k1, bfrE, 1, 1);
  RDB(b0k0, bfrE, 2, 0); RDB(b0k1, bfrE, 2, 1); RDB(b0k0, bfrE, 3, 0); RDB(b0k1, bfrE, 3, 1);
  RDA(aB0, 0, afrA, 0, 0); RDA(aB0, 0, afrA, 0, 1); RDA(aB0, 0, afrA, 1, 0); RDA(aB0, 0, afrA, 1, 1);

  // Group t ledger (R11-verified): ph0 A0(t+1), ph1 A1(t+1), ph2 B0(t+3)+
  // VMW(2), ph3 B1(t+3). @ph2-end: carry{B(t+2)}4 + A(t+1)4 + B0(t+3)2 = 10
  // -> keep 2 = B0(t+3); retires B(t+2) and A(t+1) (cross-read at ph3 after
  // the ph2-end barrier). Reads per phase: 4 afr(q+1) + 2 bfr(next tile).
  const int NITER = NT >> 1;
  const int MAIN = NITER - 2;
  for (int i = 0; i < MAIN; ++i) {
    const int t0 = i * 2;
    // even tile t0: A in aB0, consume bfrE, prefetch bfrO (buf1)
    PHASE(0, afrA, bfrE,
          RDA(aB0, 1, afrB, 0, 0), RDA(aB0, 1, afrB, 0, 1), RDA(aB0, 1, afrB, 1, 0), RDA(aB0, 1, afrB, 1, 1),
          RDB(b1k0, bfrO, 0, 0), RDB(b1k1, bfrO, 0, 1),
          SA1(aB1, 0, t0 + 1, 0), SA1(aB1, 0, t0 + 1, 1), NOWT);
    PHASE(1, afrB, bfrE,
          RDA(aB0, 2, afrA, 0, 0), RDA(aB0, 2, afrA, 0, 1), RDA(aB0, 2, afrA, 1, 0), RDA(aB0, 2, afrA, 1, 1),
          RDB(b1k0, bfrO, 1, 0), RDB(b1k1, bfrO, 1, 1),
          SA1(aB1, 1, t0 + 1, 0), SA1(aB1, 1, t0 + 1, 1), NOWT);
    PHASE(2, afrA, bfrE,
          RDA(aB0, 3, afrB, 0, 0), RDA(aB0, 3, afrB, 0, 1), RDA(aB0, 3, afrB, 1, 0), RDA(aB0, 3, afrB, 1, 1),
          RDB(b1k0, bfrO, 2, 0), RDB(b1k1, bfrO, 2, 1),
          SB1(bR0, 0, t0 + 3, 0), SB1(bR0, 0, t0 + 3, 1), VMW(2));
    PHASE(3, afrB, bfrE,
          RDA(aB1, 0, afrA, 0, 0), RDA(aB1, 0, afrA, 0, 1), RDA(aB1, 0, afrA, 1, 0), RDA(aB1, 0, afrA, 1, 1),
          RDB(b1k0, bfrO, 3, 0), RDB(b1k1, bfrO, 3, 1),
          SB1(bR0, 1, t0 + 3, 0), SB1(bR0, 1, t0 + 3, 1), NOWT);
    // odd tile t0+1: A in aB1, consume bfrO, prefetch bfrE (buf2)
    PHASE(0, afrA, bfrO,
          RDA(aB1, 1, afrB, 0, 0), RDA(aB1, 1, afrB, 0, 1), RDA(aB1, 1, afrB, 1, 0), RDA(aB1, 1, afrB, 1, 1),
          RDB(b2k0, bfrE, 0, 0), RDB(b2k1, bfrE, 0, 1),
          SA1(aB0, 0, t0 + 2, 0), SA1(aB0, 0, t0 + 2, 1), NOWT);
    PHASE(1, afrB, bfrO,
          RDA(aB1, 2, afrA, 0, 0), RDA(aB1, 2, afrA, 0, 1), RDA(aB1, 2, afrA, 1, 0), RDA(aB1, 2, afrA, 1, 1),
          RDB(b2k0, bfrE, 1, 0), RDB(b2k1, bfrE, 1, 1),
          SA1(aB0, 1, t0 + 2, 0), SA1(aB0, 1, t0 + 2, 1), NOWT);
    PHASE(2, afrA, bfrO,
          RDA(aB1, 3, afrB, 0, 0), RDA(aB1, 3, afrB, 0, 1), RDA(aB1, 3, afrB, 1, 0), RDA(aB1, 3, afrB, 1, 1),
          RDB(b2k0, bfrE, 2, 0), RDB(b2k1, bfrE, 2, 1),
          SB1(bR1, 0, t0 + 4, 0), SB1(bR1, 0, t0 + 4, 1), VMW(2));
    PHASE(3, afrB, bfrO,
          RDA(aB0, 0, afrA, 0, 0), RDA(aB0, 0, afrA, 0, 1), RDA(aB0, 0, afrA, 1, 0), RDA(aB0, 0, afrA, 1, 1),
          RDB(b2k0, bfrE, 3, 0), RDB(b2k1, bfrE, 3, 1),
          SB1(bR1, 1, t0 + 4, 0), SB1(bR1, 1, t0 + 4, 1), NOWT);
    // rotate: (buf0,buf1,buf2) <- (buf2,buf0,buf1)
    int t1 = bR0; bR0 = bR2; bR2 = bR1; bR1 = t1;
    int t2 = b0k0; b0k0 = b2k0; b2k0 = b1k0; b1k0 = t2;
    int t3 = b0k1; b0k1 = b2k1; b2k1 = b1k1; b1k1 = t3;
  }

  // ---- tail: last 2 iterations (4 tiles), guarded stages, VMW(0) ----
  for (int i = (MAIN > 0 ? MAIN : 0); i < NITER; ++i) {
    const int t0 = i * 2;
    const bool a1 = (t0 + 1 < NT);
    const bool a2 = (t0 + 2 < NT);
    const bool b3 = (t0 + 3 < NT);
    const bool b4 = (t0 + 4 < NT);
    PHASE(0, afrA, bfrE,
          RDA(aB0, 1, afrB, 0, 0), RDA(aB0, 1, afrB, 0, 1), RDA(aB0, 1, afrB, 1, 0), RDA(aB0, 1, afrB, 1, 1),
          RDB(b1k0, bfrO, 0, 0), RDB(b1k1, bfrO, 0, 1),
          { if (a1) SA1(aB1, 0, t0 + 1, 0); }, { if (a1) SA1(aB1, 0, t0 + 1, 1); }, NOWT);
    PHASE(1, afrB, bfrE,
          RDA(aB0, 2, afrA, 0, 0), RDA(aB0, 2, afrA, 0, 1), RDA(aB0, 2, afrA, 1, 0), RDA(aB0, 2, afrA, 1, 1),
          RDB(b1k0, bfrO, 1, 0), RDB(b1k1, bfrO, 1, 1),
          { if (a1) SA1(aB1, 1, t0 + 1, 0); }, { if (a1) SA1(aB1, 1, t0 + 1, 1); }, NOWT);
    PHASE(2, afrA, bfrE,
          RDA(aB0, 3, afrB, 0, 0), RDA(aB0, 3, afrB, 0, 1), RDA(aB0, 3, afrB, 1, 0), RDA(aB0, 3, afrB, 1, 1),
          RDB(b1k0, bfrO, 2, 0), RDB(b1k1, bfrO, 2, 1),
          { if (b3) SB1(bR0, 0, t0 + 3, 0); }, { if (b3) SB1(bR0, 0, t0 + 3, 1); }, VMW(0));
    PHASE(3, afrB, bfrE,
          RDA(aB1, 0, afrA, 0, 0), RDA(aB1, 0, afrA, 0, 1), RDA(aB1, 0, afrA, 1, 0), RDA(aB1, 0, afrA, 1, 1),
          RDB(b1k0, bfrO, 3, 0), RDB(b1k1, bfrO, 3, 1),
          { if (b3) SB1(bR0, 1, t0 + 3, 0); }, { if (b3) SB1(bR0, 1, t0 + 3, 1); }, NOWT);
    PHASE(0, afrA, bfrO,
          RDA(aB1, 1, afrB, 0, 0), RDA(aB1, 1, afrB, 0, 1), RDA(aB1, 1, afrB, 1, 0), RDA(aB1, 1, afrB, 1, 1),
          RDB(b2k0, bfrE, 0, 0), RDB(b2k1, bfrE, 0, 1),
          { if (a2) SA1(aB0, 0, t0 + 2, 0); }, { if (a2) SA1(aB0, 0, t0 + 2, 1); }, NOWT);
    PHASE(1, afrB, bfrO,
          RDA(aB1, 2, afrA, 0, 0), RDA(aB1, 2, afrA, 0, 1), RDA(aB1, 2, afrA, 1, 0), RDA(aB1, 2, afrA, 1, 1),
          RDB(b2k0, bfrE, 1, 0), RDB(b2k1, bfrE, 1, 1),
          { if (a2) SA1(aB0, 1, t0 + 2, 0); }, { if (a2) SA1(aB0, 1, t0 + 2, 1); }, NOWT);
    PHASE(2, afrA, bfrO,
          RDA(aB1, 3, afrB, 0, 0), RDA(aB1, 3, afrB, 0, 1), RDA(aB1, 3, afrB, 1, 0), RDA(aB1, 3, afrB, 1, 1),
          RDB(b2k0, bfrE, 2, 0), RDB(b2k1, bfrE, 2, 1),
          { if (b4) SB1(bR1, 0, t0 + 4, 0); }, { if (b4) SB1(bR1, 0, t0 + 4, 1); }, VMW(0));
    PHASE(3, afrB, bfrO,
          RDA(aB0, 0, afrA, 0, 0), RDA(aB0, 0, afrA, 0, 1), RDA(aB0, 0, afrA, 1, 0), RDA(aB0, 0, afrA, 1, 1),
          RDB(b2k0, bfrE, 3, 0), RDB(b2k1, bfrE, 3, 1),
          { if (b4) SB1(bR1, 1, t0 + 4, 0); }, { if (b4) SB1(bR1, 1, t0 + 4, 1); }, NOWT);
    int t1 = bR0; bR0 = bR2; bR2 = bR1; bR1 = t1;
    int t2 = b0k0; b0k0 = b2k0; b2k0 = b1k0; b1k0 = t2;
    int t3 = b0k1; b0k1 = b2k1; b2k1 = b1k1; b1k1 = t3;
  }

  // epilogue: C/D layout col = lane&15, row = (lane>>4)*4 + j
  const int cm = (lane >> 4) * 4;
  const int cn = lane & 15;
  float bv[4];
#pragma unroll
  for (int ni = 0; ni < 4; ++ni) bv[ni] = bias[bcol + wc * 64 + ni * 16 + cn];

#pragma unroll
  for (int mi = 0; mi < 8; ++mi) {
    const long row0 = brow + wr * 128 + mi * 16 + cm;
#pragma unroll
    for (int ni = 0; ni < 4; ++ni) {
      const long col = bcol + wc * 64 + ni * 16 + cn;
#pragma unroll
      for (int j = 0; j < 4; ++j)
        C[(row0 + j) * (long)Nout + col] = acc[mi][ni][j] + bv[ni];
    }
  }
#undef SA1
#undef SB1
#undef RDA
#undef RDB
#undef MFMA1
#undef MM2
#undef PHASE
}

// ---- 128x128 m97-structure fallback (verified in R1) -----------------------
__global__ __launch_bounds__(256, 2) void gemm128_kernel(
    const u16* __restrict__ Xb, const u16* __restrict__ Wb,
    const float* __restrict__ bias, float* __restrict__ C,
    int Nout, int Kin) {
  __shared__ __align__(16) u16 As[128 * 32];
  __shared__ __align__(16) u16 Bs[128 * 32];
  const int tid  = threadIdx.x;
  const int lane = tid & 63;
  const int wave = tid >> 6;
  const int wr = wave >> 1, wc = wave & 1;
  const int nwg = gridDim.x, bid = blockIdx.x;
  const int q = nwg >> 3, r8 = nwg & 7;
  const int xcd = bid & 7;
  const int wg = (xcd < r8 ? xcd * (q + 1) : r8 * (q + 1) + (xcd - r8) * q) + (bid >> 3);
  const int tiles_n = Nout / 128;
  const long brow = (long)(wg / tiles_n) * 128;
  const long bcol = (long)(wg % tiles_n) * 128;
  const int f0 = tid * 16, f1 = f0 + 4096;
  const size_t rowbytes = (size_t)Kin * 2;
  const char* gA0 = (const char*)Xb + (size_t)(brow + (f0 >> 6)) * rowbytes + (f0 & 63);
  const char* gA1 = (const char*)Xb + (size_t)(brow + (f1 >> 6)) * rowbytes + (f1 & 63);
  const char* gB0 = (const char*)Wb + (size_t)(bcol + (f0 >> 6)) * rowbytes + (f0 & 63);
  const char* gB1 = (const char*)Wb + (size_t)(bcol + (f1 >> 6)) * rowbytes + (f1 & 63);
  char* lA0 = (char*)As + f0; char* lA1 = (char*)As + f1;
  char* lB0 = (char*)Bs + f0; char* lB1 = (char*)Bs + f1;
  const int fr = lane & 15, kb = (lane >> 4) * 16;
  const char* aptr[4]; const char* bptr[4];
#pragma unroll
  for (int i = 0; i < 4; ++i) {
    aptr[i] = (const char*)As + (wr * 64 + i * 16 + fr) * 64 + kb;
    bptr[i] = (const char*)Bs + (wc * 64 + i * 16 + fr) * 64 + kb;
  }
  f32x4 acc[4][4] = {};
  for (int kk = 0; kk < Kin; kk += 32) {
    const size_t ko = (size_t)kk * 2;
    gld_lds16(gA0 + ko, lA0); gld_lds16(gA1 + ko, lA1);
    gld_lds16(gB0 + ko, lB0); gld_lds16(gB1 + ko, lB1);
    __syncthreads();
    bf16x8 a[4], b[4];
#pragma unroll
    for (int i = 0; i < 4; ++i) a[i] = *(const bf16x8*)aptr[i];
#pragma unroll
    for (int i = 0; i < 4; ++i) b[i] = *(const bf16x8*)bptr[i];
#pragma unroll
    for (int mi = 0; mi < 4; ++mi)
#pragma unroll
      for (int ni = 0; ni < 4; ++ni)
        acc[mi][ni] = __builtin_amdgcn_mfma_f32_16x16x32_bf16(a[mi], b[ni], acc[mi][ni], 0, 0, 0);
    __syncthreads();
  }
  const int cm = (lane >> 4) * 4, cn = lane & 15;
  float bv[4];
#pragma unroll
  for (int ni = 0; ni < 4; ++ni) bv[ni] = bias[bcol + wc * 64 + ni * 16 + cn];
#pragma unroll
  for (int mi = 0; mi < 4; ++mi) {
    const long row0 = brow + wr * 64 + mi * 16 + cm;
#pragma unroll
    for (int ni = 0; ni < 4; ++ni) {
      const long col = bcol + wc * 64 + ni * 16 + cn;
#pragma unroll
      for (int j = 0; j < 4; ++j)
        C[(row0 + j) * (long)Nout + col] = acc[mi][ni][j] + bv[ni];
    }
  }
}

// ---- naive fallback --------------------------------------------------------
__global__ void fallback_kernel(const float* __restrict__ x, const float* __restrict__ values,
                                const int* __restrict__ widx, const float* __restrict__ bias,
                                float* __restrict__ out, const int* __restrict__ flag,
                                int NT, int IF, int OF) {
  const int o = blockIdx.x * blockDim.x + threadIdx.x;
  const int t = blockIdx.y;
  if (o >= OF || t >= NT) return;
  const bool is32 = (*flag != 0);
  const float* xr = x + (size_t)t * IF;
  float sum = 0.f;
  if (is32) {
    const int* w = widx + (size_t)o * IF;
    for (int k = 0; k < IF; ++k) sum += xr[k] * values[w[k]];
  } else {
    const long long* w = (const long long*)widx + (size_t)o * IF;
    for (int k = 0; k < IF; ++k) sum += xr[k] * values[(int)w[k]];
  }
  out[(size_t)t * OF + o] = sum + bias[o];
}

extern "C" void kernel_launch(void* const* d_in, const int* in_sizes, int n_in,
                              void* d_out, int out_size, void* d_ws, size_t ws_size,
                              hipStream_t stream) {
  const float* x      = (const float*)d_in[0];
  const float* values = (const float*)d_in[1];
  const int*   widx   = (const int*)d_in[2];
  const float* bias   = (const float*)d_in[3];
  float* out = (float*)d_out;

  const long xsz = in_sizes[0];
  const int  OF  = in_sizes[3];
  const long wsz = in_sizes[2];
  const int  IF  = (int)(wsz / OF);
  const int  NTOK = (int)(xsz / IF);

  u16* xb = (u16*)d_ws;
  u16* wb = xb + (size_t)NTOK * IF;
  int* flag = (int*)(wb + (size_t)OF * IF);
  const size_t need = ((size_t)NTOK * IF + (size_t)OF * IF) * sizeof(u16) + 64;

  const bool pre_ok = (ws_size >= need) && ((xsz % 8) == 0) && ((wsz % 4) == 0);
  const bool f256 = pre_ok && (IF % 128 == 0) && (IF >= 256) &&
                    (NTOK % 256 == 0) && (OF % 256 == 0);
  const bool f128 = pre_ok && (IF % 32 == 0) && (NTOK % 128 == 0) && (OF % 128 == 0);

  if (f256 || f128) {
    hipLaunchKernelGGL(detect_idx_width, dim3(1), dim3(64), 0, stream,
                       (const unsigned*)widx, flag);
    hipLaunchKernelGGL(prepass_kernel, dim3(2048), dim3(256), 0, stream,
                       (const float4*)x, xb, xsz / 8,
                       (const int4*)widx, values, wb, (const int*)flag, wsz / 4);
    if (f256) {
      const int grid = (NTOK / 256) * (OF / 256);
      hipLaunchKernelGGL(gemm256_kernel, dim3(grid), dim3(512), 0, stream,
                         xb, wb, bias, out, OF, IF);
    } else {
      const int grid = (NTOK / 128) * (OF / 128);
      hipLaunchKernelGGL(gemm128_kernel, dim3(grid), dim3(256), 0, stream,
                         xb, wb, bias, out, OF, IF);
    }
  } else {
    int* flag2 = (int*)d_ws;
    hipLaunchKernelGGL(detect_idx_width, dim3(1), dim3(64), 0, stream,
                       (const unsigned*)widx, flag2);
    hipLaunchKernelGGL(fallback_kernel, dim3((OF + 255) / 256, NTOK), dim3(256), 0, stream,
                       x, values, widx, bias, out, (const int*)flag2, NTOK, IF, OF);
  }
}

// Round 17
// 154.369 us; speedup vs baseline: 1.0657x; 1.0657x over previous
//
#include <hip/hip_runtime.h>
#include <hip/hip_bf16.h>
#include <stdint.h>

typedef unsigned short u16;
typedef __bf16 bf16x8 __attribute__((ext_vector_type(8)));
typedef float  f32x4  __attribute__((ext_vector_type(4)));
typedef u16    u16x8  __attribute__((ext_vector_type(8)));
typedef u16    u16x4  __attribute__((ext_vector_type(4)));

// float -> bf16 RNE
__device__ __forceinline__ u16 f2bf(float f) {
  union { float f; unsigned u; } v; v.f = f;
  unsigned u = v.u;
  unsigned r = u + 0x7FFFu + ((u >> 16) & 1u);
  return (u16)(r >> 16);
}

__device__ __forceinline__ void gld_lds16(const void* g, void* l) {
  __builtin_amdgcn_global_load_lds(
      (const __attribute__((address_space(1))) void*)g,
      (__attribute__((address_space(3))) void*)l, 16, 0, 0);
}

// ---- detect int32 vs int64 index storage ----------------------------------
__global__ void detect_idx_width(const unsigned* __restrict__ w, int* __restrict__ flag) {
  unsigned v = w[threadIdx.x * 2 + 1];
  unsigned long long any = __ballot(v != 0u);
  if (threadIdx.x == 0) *flag = (any != 0ull) ? 1 : 0;  // 1 = int32, 0 = int64
}

// ---- fused prepass: x f32->bf16 AND W dequant (R11 verified best total) ----
__global__ __launch_bounds__(256) void prepass_kernel(
    const float4* __restrict__ x, u16* __restrict__ xb, long n8,
    const int4* __restrict__ widx, const float* __restrict__ values,
    u16* __restrict__ wb, const int* __restrict__ flag, long n4) {
  const long gid = (long)blockIdx.x * blockDim.x + threadIdx.x;
  const long stride = (long)gridDim.x * blockDim.x;
  for (long i = gid; i < n8; i += stride) {
    float4 a = x[2 * i];
    float4 b = x[2 * i + 1];
    u16x8 r;
    r[0] = f2bf(a.x); r[1] = f2bf(a.y); r[2] = f2bf(a.z); r[3] = f2bf(a.w);
    r[4] = f2bf(b.x); r[5] = f2bf(b.y); r[6] = f2bf(b.z); r[7] = f2bf(b.w);
    *(u16x8*)(xb + 8 * i) = r;
  }
  const bool is32 = (*flag != 0);
  for (long i = gid; i < n4; i += stride) {
    int i0, i1, i2, i3;
    if (is32) {
      int4 v = widx[i];
      i0 = v.x; i1 = v.y; i2 = v.z; i3 = v.w;
    } else {
      int4 a = widx[2 * i];
      int4 b = widx[2 * i + 1];
      i0 = a.x; i1 = a.z; i2 = b.x; i3 = b.z;
    }
    u16x4 r;
    r[0] = f2bf(values[i0]); r[1] = f2bf(values[i1]);
    r[2] = f2bf(values[i2]); r[3] = f2bf(values[i3]);
    *(u16x4*)(wb + 4 * i) = r;
  }
}

// ===========================================================================
// 256x256 bf16 GEMM — R17 = R12's verified GEMM (106.2us, MfmaUtil 58-60%,
// session best): T19 MFMA<->mem issue interleave via sched_group_barrier,
// 1 barrier/phase, counted VMW(2) ledger, hoisted LDS read addresses.
// No setprio (R16: negative). Combined with fused prepass (R11 best total).
// ===========================================================================
#define VMW(n) asm volatile("s_waitcnt vmcnt(" #n ")" ::: "memory")
#define PH_BAR asm volatile("s_barrier" ::: "memory")
#define SGB(m, n) __builtin_amdgcn_sched_group_barrier((m), (n), 0)
#define NOWT (void)0

__global__ __launch_bounds__(512, 1) void gemm256_kernel(
    const u16* __restrict__ Xb, const u16* __restrict__ Wb,
    const float* __restrict__ bias, float* __restrict__ C,
    int Nout, int Kin) {
  __shared__ __align__(16) char lds[163840];  // A:[0,64K) 2 bufs; B:[64K,160K) 3 bufs

  const int tid  = threadIdx.x;
  const int lane = tid & 63;
  const int wave = tid >> 6;
  const int wr = wave >> 2;   // 0..1  (M half)
  const int wc = wave & 3;    // 0..3  (N quarter)

  // bijective XCD swizzle (m204)
  const int nwg = gridDim.x;
  const int bid = blockIdx.x;
  const int q8 = nwg >> 3, r8 = nwg & 7;
  const int xcd = bid & 7;
  const int wg = (xcd < r8 ? xcd * (q8 + 1) : r8 * (q8 + 1) + (xcd - r8) * q8) + (bid >> 3);

  const int tiles_n = Nout / 256;
  const long brow = (long)(wg / tiles_n) * 256;
  const long bcol = (long)(wg % tiles_n) * 256;

  const long rowb  = (long)Kin * 2;     // row bytes
  const long rstep = 64 * rowb;         // +64 rows (uniform)
  const long hstep = 128 * rowb;        // +128 rows (uniform)

  // staging: inverse-swizzled global source + linear LDS dest (rule #21)
  const int f0  = tid * 16;
  const int f1  = f0 + 8192;
  const int rS0 = f0 >> 7;
  const int cS  = (f0 & 127) ^ ((rS0 & 7) << 4);
  const int voff = (int)(rS0 * rowb) + cS;

  const char* uA = (const char*)Xb + (size_t)brow * rowb;
  const char* uB = (const char*)Wb + (size_t)bcol * rowb;

// single gld_lds (h = row-half source, part = rows 0-63 / 64-127)
#define SA1(base_, h, t, part) \
  gld_lds16(uA + (size_t)(h) * hstep + (size_t)(t) * 128 + ((part) ? rstep : 0) + voff, \
            lds + (base_) + (h) * 16384 + ((part) ? f1 : f0))
#define SB1(base_, h, t, part) \
  gld_lds16(uB + (size_t)(h) * hstep + (size_t)(t) * 128 + ((part) ? rstep : 0) + voff, \
            lds + (base_) + (h) * 16384 + ((part) ? f1 : f0))

  // fragment read addressing (swizzled), hoisted to address ints
  const int fr   = lane & 15;
  const int kb   = (lane >> 4) * 16;
  const int xsw  = (fr & 7) << 4;
  const int colx0 = kb ^ xsw;
  const int colx1 = (64 + kb) ^ xsw;
  const int aOff = wr * 16384 + fr * 128;
  const int bOff = (wc >> 1) * 16384 + ((wc & 1) * 64 + fr) * 128;
  const int aAdr0 = aOff + colx0;
  const int aAdr1 = aOff + colx1;
  int b0k0 = 65536  + bOff + colx0, b0k1 = 65536  + bOff + colx1;
  int b1k0 = 98304  + bOff + colx0, b1k1 = 98304  + bOff + colx1;
  int b2k0 = 131072 + bOff + colx0, b2k1 = 131072 + bOff + colx1;

  bf16x8 afrA[2][2];   // MFMA(q) consumes afrA if q even, afrB if q odd
  bf16x8 afrB[2][2];
  bf16x8 bfrE[4][2];   // B-frags, even tiles
  bf16x8 bfrO[4][2];   // B-frags, odd tiles
  f32x4  acc[8][4] = {};

#define RDA(aBase_, q, DST, m2, ks) \
  DST[(m2)][(ks)] = *(const bf16x8*)(lds + ((ks) ? aAdr1 : aAdr0) + (aBase_) + (q) * 4096 + (m2) * 2048)
#define RDB(bk, DST, ni, ks) \
  DST[(ni)][(ks)] = *(const bf16x8*)(lds + (bk) + (ni) * 2048)

#define MFMA1(d, a, b) d = __builtin_amdgcn_mfma_f32_16x16x32_bf16((a), (b), (d), 0, 0, 0)
#define MM2(q, m2, ni, AF, BF) { \
  MFMA1(acc[(q)*2+(m2)][(ni)], AF[(m2)][0], BF[(ni)][0]); \
  MFMA1(acc[(q)*2+(m2)][(ni)], AF[(m2)][1], BF[(ni)][1]); }

// Phase: 16 MFMA interleaved 2:1 with 6 ds_reads + 2 gld_lds (T19 pattern).
#define PHASE(q, AF, BF, R0, R1, R2, R3, R4, R5, S0, S1, WT) { \
  MM2(q, 0, 0, AF, BF); SGB(0x8, 2); R0; SGB(0x100, 1); \
  MM2(q, 1, 0, AF, BF); SGB(0x8, 2); R1; SGB(0x100, 1); \
  MM2(q, 0, 1, AF, BF); SGB(0x8, 2); R2; SGB(0x100, 1); \
  MM2(q, 1, 1, AF, BF); SGB(0x8, 2); R3; SGB(0x100, 1); \
  MM2(q, 0, 2, AF, BF); SGB(0x8, 2); R4; SGB(0x100, 1); \
  MM2(q, 1, 2, AF, BF); SGB(0x8, 2); R5; SGB(0x100, 1); \
  MM2(q, 0, 3, AF, BF); SGB(0x8, 2); S0; SGB(0x70, 1); \
  MM2(q, 1, 3, AF, BF); SGB(0x8, 2); S1; SGB(0x70, 1); \
  WT; PH_BAR; }

  const int aB0 = 0, aB1 = 32768;
  int bR0 = 65536, bR1 = 98304, bR2 = 131072;  // LDS byte bases for staging
  const int NT = Kin >> 6;

  // prologue: A(0)->aB0, B(0..2); drain; preload bfrE=B(0), afrA=A(0,q0)
  SA1(aB0, 0, 0, 0); SA1(aB0, 0, 0, 1); SA1(aB0, 1, 0, 0); SA1(aB0, 1, 0, 1);
  SB1(bR0, 0, 0, 0); SB1(bR0, 0, 0, 1); SB1(bR0, 1, 0, 0); SB1(bR0, 1, 0, 1);
  SB1(bR1, 0, 1, 0); SB1(bR1, 0, 1, 1); SB1(bR1, 1, 1, 0); SB1(bR1, 1, 1, 1);
  SB1(bR2, 0, 2, 0); SB1(bR2, 0, 2, 1); SB1(bR2, 1, 2, 0); SB1(bR2, 1, 2, 1);
  VMW(0);
  PH_BAR;
  RDB(b0k0, bfrE, 0, 0); RDB(b0k1, bfrE, 0, 1); RDB(b0k0, bfrE, 1, 0); RDB(b0k1, bfrE, 1, 1);
  RDB(b0k0, bfrE, 2, 0); RDB(b0k1, bfrE, 2, 1); RDB(b0k0, bfrE, 3, 0); RDB(b0k1, bfrE, 3, 1);
  RDA(aB0, 0, afrA, 0, 0); RDA(aB0, 0, afrA, 0, 1); RDA(aB0, 0, afrA, 1, 0); RDA(aB0, 0, afrA, 1, 1);

  // Group t ledger (R11-verified): ph0 A0(t+1), ph1 A1(t+1), ph2 B0(t+3)+
  // VMW(2), ph3 B1(t+3). @ph2-end: carry{B(t+2)}4 + A(t+1)4 + B0(t+3)2 = 10
  // -> keep 2 = B0(t+3); retires B(t+2) and A(t+1) (cross-read at ph3 after
  // the ph2-end barrier). Reads per phase: 4 afr(q+1) + 2 bfr(next tile).
  const int NITER = NT >> 1;
  const int MAIN = NITER - 2;
  for (int i = 0; i < MAIN; ++i) {
    const int t0 = i * 2;
    // even tile t0: A in aB0, consume bfrE, prefetch bfrO (buf1)
    PHASE(0, afrA, bfrE,
          RDA(aB0, 1, afrB, 0, 0), RDA(aB0, 1, afrB, 0, 1), RDA(aB0, 1, afrB, 1, 0), RDA(aB0, 1, afrB, 1, 1),
          RDB(b1k0, bfrO, 0, 0), RDB(b1k1, bfrO, 0, 1),
          SA1(aB1, 0, t0 + 1, 0), SA1(aB1, 0, t0 + 1, 1), NOWT);
    PHASE(1, afrB, bfrE,
          RDA(aB0, 2, afrA, 0, 0), RDA(aB0, 2, afrA, 0, 1), RDA(aB0, 2, afrA, 1, 0), RDA(aB0, 2, afrA, 1, 1),
          RDB(b1k0, bfrO, 1, 0), RDB(b1k1, bfrO, 1, 1),
          SA1(aB1, 1, t0 + 1, 0), SA1(aB1, 1, t0 + 1, 1), NOWT);
    PHASE(2, afrA, bfrE,
          RDA(aB0, 3, afrB, 0, 0), RDA(aB0, 3, afrB, 0, 1), RDA(aB0, 3, afrB, 1, 0), RDA(aB0, 3, afrB, 1, 1),
          RDB(b1k0, bfrO, 2, 0), RDB(b1k1, bfrO, 2, 1),
          SB1(bR0, 0, t0 + 3, 0), SB1(bR0, 0, t0 + 3, 1), VMW(2));
    PHASE(3, afrB, bfrE,
          RDA(aB1, 0, afrA, 0, 0), RDA(aB1, 0, afrA, 0, 1), RDA(aB1, 0, afrA, 1, 0), RDA(aB1, 0, afrA, 1, 1),
          RDB(b1k0, bfrO, 3, 0), RDB(b1k1, bfrO, 3, 1),
          SB1(bR0, 1, t0 + 3, 0), SB1(bR0, 1, t0 + 3, 1), NOWT);
    // odd tile t0+1: A in aB1, consume bfrO, prefetch bfrE (buf2)
    PHASE(0, afrA, bfrO,
          RDA(aB1, 1, afrB, 0, 0), RDA(aB1, 1, afrB, 0, 1), RDA(aB1, 1, afrB, 1, 0), RDA(aB1, 1, afrB, 1, 1),
          RDB(b2k0, bfrE, 0, 0), RDB(b2k1, bfrE, 0, 1),
          SA1(aB0, 0, t0 + 2, 0), SA1(aB0, 0, t0 + 2, 1), NOWT);
    PHASE(1, afrB, bfrO,
          RDA(aB1, 2, afrA, 0, 0), RDA(aB1, 2, afrA, 0, 1), RDA(aB1, 2, afrA, 1, 0), RDA(aB1, 2, afrA, 1, 1),
          RDB(b2k0, bfrE, 1, 0), RDB(b2k1, bfrE, 1, 1),
          SA1(aB0, 1, t0 + 2, 0), SA1(aB0, 1, t0 + 2, 1), NOWT);
    PHASE(2, afrA, bfrO,
          RDA(aB1, 3, afrB, 0, 0), RDA(aB1, 3, afrB, 0, 1), RDA(aB1, 3, afrB, 1, 0), RDA(aB1, 3, afrB, 1, 1),
          RDB(b2k0, bfrE, 2, 0), RDB(b2k1, bfrE, 2, 1),
          SB1(bR1, 0, t0 + 4, 0), SB1(bR1, 0, t0 + 4, 1), VMW(2));
    PHASE(3, afrB, bfrO,
          RDA(aB0, 0, afrA, 0, 0), RDA(aB0, 0, afrA, 0, 1), RDA(aB0, 0, afrA, 1, 0), RDA(aB0, 0, afrA, 1, 1),
          RDB(b2k0, bfrE, 3, 0), RDB(b2k1, bfrE, 3, 1),
          SB1(bR1, 1, t0 + 4, 0), SB1(bR1, 1, t0 + 4, 1), NOWT);
    // rotate: (buf0,buf1,buf2) <- (buf2,buf0,buf1)
    int t1 = bR0; bR0 = bR2; bR2 = bR1; bR1 = t1;
    int t2 = b0k0; b0k0 = b2k0; b2k0 = b1k0; b1k0 = t2;
    int t3 = b0k1; b0k1 = b2k1; b2k1 = b1k1; b1k1 = t3;
  }

  // ---- tail: last 2 iterations (4 tiles), guarded stages, VMW(0) ----
  for (int i = (MAIN > 0 ? MAIN : 0); i < NITER; ++i) {
    const int t0 = i * 2;
    const bool a1 = (t0 + 1 < NT);
    const bool a2 = (t0 + 2 < NT);
    const bool b3 = (t0 + 3 < NT);
    const bool b4 = (t0 + 4 < NT);
    PHASE(0, afrA, bfrE,
          RDA(aB0, 1, afrB, 0, 0), RDA(aB0, 1, afrB, 0, 1), RDA(aB0, 1, afrB, 1, 0), RDA(aB0, 1, afrB, 1, 1),
          RDB(b1k0, bfrO, 0, 0), RDB(b1k1, bfrO, 0, 1),
          { if (a1) SA1(aB1, 0, t0 + 1, 0); }, { if (a1) SA1(aB1, 0, t0 + 1, 1); }, NOWT);
    PHASE(1, afrB, bfrE,
          RDA(aB0, 2, afrA, 0, 0), RDA(aB0, 2, afrA, 0, 1), RDA(aB0, 2, afrA, 1, 0), RDA(aB0, 2, afrA, 1, 1),
          RDB(b1k0, bfrO, 1, 0), RDB(b1k1, bfrO, 1, 1),
          { if (a1) SA1(aB1, 1, t0 + 1, 0); }, { if (a1) SA1(aB1, 1, t0 + 1, 1); }, NOWT);
    PHASE(2, afrA, bfrE,
          RDA(aB0, 3, afrB, 0, 0), RDA(aB0, 3, afrB, 0, 1), RDA(aB0, 3, afrB, 1, 0), RDA(aB0, 3, afrB, 1, 1),
          RDB(b1k0, bfrO, 2, 0), RDB(b1k1, bfrO, 2, 1),
          { if (b3) SB1(bR0, 0, t0 + 3, 0); }, { if (b3) SB1(bR0, 0, t0 + 3, 1); }, VMW(0));
    PHASE(3, afrB, bfrE,
          RDA(aB1, 0, afrA, 0, 0), RDA(aB1, 0, afrA, 0, 1), RDA(aB1, 0, afrA, 1, 0), RDA(aB1, 0, afrA, 1, 1),
          RDB(b1k0, bfrO, 3, 0), RDB(b1k1, bfrO, 3, 1),
          { if (b3) SB1(bR0, 1, t0 + 3, 0); }, { if (b3) SB1(bR0, 1, t0 + 3, 1); }, NOWT);
    PHASE(0, afrA, bfrO,
          RDA(aB1, 1, afrB, 0, 0), RDA(aB1, 1, afrB, 0, 1), RDA(aB1, 1, afrB, 1, 0), RDA(aB1, 1, afrB, 1, 1),
          RDB(b2k0, bfrE, 0, 0), RDB(b2k1, bfrE, 0, 1),
          { if (a2) SA1(aB0, 0, t0 + 2, 0); }, { if (a2) SA1(aB0, 0, t0 + 2, 1); }, NOWT);
    PHASE(1, afrB, bfrO,
          RDA(aB1, 2, afrA, 0, 0), RDA(aB1, 2, afrA, 0, 1), RDA(aB1, 2, afrA, 1, 0), RDA(aB1, 2, afrA, 1, 1),
          RDB(b2k0, bfrE, 1, 0), RDB(b2k1, bfrE, 1, 1),
          { if (a2) SA1(aB0, 1, t0 + 2, 0); }, { if (a2) SA1(aB0, 1, t0 + 2, 1); }, NOWT);
    PHASE(2, afrA, bfrO,
          RDA(aB1, 3, afrB, 0, 0), RDA(aB1, 3, afrB, 0, 1), RDA(aB1, 3, afrB, 1, 0), RDA(aB1, 3, afrB, 1, 1),
          RDB(b2k0, bfrE, 2, 0), RDB(b2k1, bfrE, 2, 1),
          { if (b4) SB1(bR1, 0, t0 + 4, 0); }, { if (b4) SB1(bR1, 0, t0 + 4, 1); }, VMW(0));
    PHASE(3, afrB, bfrO,
          RDA(aB0, 0, afrA, 0, 0), RDA(aB0, 0, afrA, 0, 1), RDA(aB0, 0, afrA, 1, 0), RDA(aB0, 0, afrA, 1, 1),
          RDB(b2k0, bfrE, 3, 0), RDB(b2k1, bfrE, 3, 1),
          { if (b4) SB1(bR1, 1, t0 + 4, 0); }, { if (b4) SB1(bR1, 1, t0 + 4, 1); }, NOWT);
    int t1 = bR0; bR0 = bR2; bR2 = bR1; bR1 = t1;
    int t2 = b0k0; b0k0 = b2k0; b2k0 = b1k0; b1k0 = t2;
    int t3 = b0k1; b0k1 = b2k1; b2k1 = b1k1; b1k1 = t3;
  }

  // epilogue: C/D layout col = lane&15, row = (lane>>4)*4 + j
  const int cm = (lane >> 4) * 4;
  const int cn = lane & 15;
  float bv[4];
#pragma unroll
  for (int ni = 0; ni < 4; ++ni) bv[ni] = bias[bcol + wc * 64 + ni * 16 + cn];

#pragma unroll
  for (int mi = 0; mi < 8; ++mi) {
    const long row0 = brow + wr * 128 + mi * 16 + cm;
#pragma unroll
    for (int ni = 0; ni < 4; ++ni) {
      const long col = bcol + wc * 64 + ni * 16 + cn;
#pragma unroll
      for (int j = 0; j < 4; ++j)
        C[(row0 + j) * (long)Nout + col] = acc[mi][ni][j] + bv[ni];
    }
  }
#undef SA1
#undef SB1
#undef RDA
#undef RDB
#undef MFMA1
#undef MM2
#undef PHASE
}

// ---- 128x128 m97-structure fallback (verified in R1) -----------------------
__global__ __launch_bounds__(256, 2) void gemm128_kernel(
    const u16* __restrict__ Xb, const u16* __restrict__ Wb,
    const float* __restrict__ bias, float* __restrict__ C,
    int Nout, int Kin) {
  __shared__ __align__(16) u16 As[128 * 32];
  __shared__ __align__(16) u16 Bs[128 * 32];
  const int tid  = threadIdx.x;
  const int lane = tid & 63;
  const int wave = tid >> 6;
  const int wr = wave >> 1, wc = wave & 1;
  const int nwg = gridDim.x, bid = blockIdx.x;
  const int q = nwg >> 3, r8 = nwg & 7;
  const int xcd = bid & 7;
  const int wg = (xcd < r8 ? xcd * (q + 1) : r8 * (q + 1) + (xcd - r8) * q) + (bid >> 3);
  const int tiles_n = Nout / 128;
  const long brow = (long)(wg / tiles_n) * 128;
  const long bcol = (long)(wg % tiles_n) * 128;
  const int f0 = tid * 16, f1 = f0 + 4096;
  const size_t rowbytes = (size_t)Kin * 2;
  const char* gA0 = (const char*)Xb + (size_t)(brow + (f0 >> 6)) * rowbytes + (f0 & 63);
  const char* gA1 = (const char*)Xb + (size_t)(brow + (f1 >> 6)) * rowbytes + (f1 & 63);
  const char* gB0 = (const char*)Wb + (size_t)(bcol + (f0 >> 6)) * rowbytes + (f0 & 63);
  const char* gB1 = (const char*)Wb + (size_t)(bcol + (f1 >> 6)) * rowbytes + (f1 & 63);
  char* lA0 = (char*)As + f0; char* lA1 = (char*)As + f1;
  char* lB0 = (char*)Bs + f0; char* lB1 = (char*)Bs + f1;
  const int fr = lane & 15, kb = (lane >> 4) * 16;
  const char* aptr[4]; const char* bptr[4];
#pragma unroll
  for (int i = 0; i < 4; ++i) {
    aptr[i] = (const char*)As + (wr * 64 + i * 16 + fr) * 64 + kb;
    bptr[i] = (const char*)Bs + (wc * 64 + i * 16 + fr) * 64 + kb;
  }
  f32x4 acc[4][4] = {};
  for (int kk = 0; kk < Kin; kk += 32) {
    const size_t ko = (size_t)kk * 2;
    gld_lds16(gA0 + ko, lA0); gld_lds16(gA1 + ko, lA1);
    gld_lds16(gB0 + ko, lB0); gld_lds16(gB1 + ko, lB1);
    __syncthreads();
    bf16x8 a[4], b[4];
#pragma unroll
    for (int i = 0; i < 4; ++i) a[i] = *(const bf16x8*)aptr[i];
#pragma unroll
    for (int i = 0; i < 4; ++i) b[i] = *(const bf16x8*)bptr[i];
#pragma unroll
    for (int mi = 0; mi < 4; ++mi)
#pragma unroll
      for (int ni = 0; ni < 4; ++ni)
        acc[mi][ni] = __builtin_amdgcn_mfma_f32_16x16x32_bf16(a[mi], b[ni], acc[mi][ni], 0, 0, 0);
    __syncthreads();
  }
  const int cm = (lane >> 4) * 4, cn = lane & 15;
  float bv[4];
#pragma unroll
  for (int ni = 0; ni < 4; ++ni) bv[ni] = bias[bcol + wc * 64 + ni * 16 + cn];
#pragma unroll
  for (int mi = 0; mi < 4; ++mi) {
    const long row0 = brow + wr * 64 + mi * 16 + cm;
#pragma unroll
    for (int ni = 0; ni < 4; ++ni) {
      const long col = bcol + wc * 64 + ni * 16 + cn;
#pragma unroll
      for (int j = 0; j < 4; ++j)
        C[(row0 + j) * (long)Nout + col] = acc[mi][ni][j] + bv[ni];
    }
  }
}

// ---- naive fallback --------------------------------------------------------
__global__ void fallback_kernel(const float* __restrict__ x, const float* __restrict__ values,
                                const int* __restrict__ widx, const float* __restrict__ bias,
                                float* __restrict__ out, const int* __restrict__ flag,
                                int NT, int IF, int OF) {
  const int o = blockIdx.x * blockDim.x + threadIdx.x;
  const int t = blockIdx.y;
  if (o >= OF || t >= NT) return;
  const bool is32 = (*flag != 0);
  const float* xr = x + (size_t)t * IF;
  float sum = 0.f;
  if (is32) {
    const int* w = widx + (size_t)o * IF;
    for (int k = 0; k < IF; ++k) sum += xr[k] * values[w[k]];
  } else {
    const long long* w = (const long long*)widx + (size_t)o * IF;
    for (int k = 0; k < IF; ++k) sum += xr[k] * values[(int)w[k]];
  }
  out[(size_t)t * OF + o] = sum + bias[o];
}

extern "C" void kernel_launch(void* const* d_in, const int* in_sizes, int n_in,
                              void* d_out, int out_size, void* d_ws, size_t ws_size,
                              hipStream_t stream) {
  const float* x      = (const float*)d_in[0];
  const float* values = (const float*)d_in[1];
  const int*   widx   = (const int*)d_in[2];
  const float* bias   = (const float*)d_in[3];
  float* out = (float*)d_out;

  const long xsz = in_sizes[0];
  const int  OF  = in_sizes[3];
  const long wsz = in_sizes[2];
  const int  IF  = (int)(wsz / OF);
  const int  NTOK = (int)(xsz / IF);

  u16* xb = (u16*)d_ws;
  u16* wb = xb + (size_t)NTOK * IF;
  int* flag = (int*)(wb + (size_t)OF * IF);
  const size_t need = ((size_t)NTOK * IF + (size_t)OF * IF) * sizeof(u16) + 64;

  const bool pre_ok = (ws_size >= need) && ((xsz % 8) == 0) && ((wsz % 4) == 0);
  const bool f256 = pre_ok && (IF % 128 == 0) && (IF >= 256) &&
                    (NTOK % 256 == 0) && (OF % 256 == 0);
  const bool f128 = pre_ok && (IF % 32 == 0) && (NTOK % 128 == 0) && (OF % 128 == 0);

  if (f256 || f128) {
    hipLaunchKernelGGL(detect_idx_width, dim3(1), dim3(64), 0, stream,
                       (const unsigned*)widx, flag);
    hipLaunchKernelGGL(prepass_kernel, dim3(2048), dim3(256), 0, stream,
                       (const float4*)x, xb, xsz / 8,
                       (const int4*)widx, values, wb, (const int*)flag, wsz / 4);
    if (f256) {
      const int grid = (NTOK / 256) * (OF / 256);
      hipLaunchKernelGGL(gemm256_kernel, dim3(grid), dim3(512), 0, stream,
                         xb, wb, bias, out, OF, IF);
    } else {
      const int grid = (NTOK / 128) * (OF / 128);
      hipLaunchKernelGGL(gemm128_kernel, dim3(grid), dim3(256), 0, stream,
                         xb, wb, bias, out, OF, IF);
    }
  } else {
    int* flag2 = (int*)d_ws;
    hipLaunchKernelGGL(detect_idx_width, dim3(1), dim3(64), 0, stream,
                       (const unsigned*)widx, flag2);
    hipLaunchKernelGGL(fallback_kernel, dim3((OF + 255) / 256, NTOK), dim3(256), 0, stream,
                       x, values, widx, bias, out, (const int*)flag2, NTOK, IF, OF);
  }
}